// Round 2
// 1999.009 us; speedup vs baseline: 1.3843x; 1.3843x over previous
//
#include <hip/hip_runtime.h>
#include <cstddef>
#include <cstdint>

#define NB 2
#define SEQ 2048
#define HID 1024
#define HEADS 16
#define HD 64
#define PF 4096
#define EPSV 1e-5f
#define ATT_SCALE 0.125f   // 1/sqrt(64)
#define MB (1024ull*1024ull)

typedef __attribute__((ext_vector_type(4))) float f32x4;
typedef __attribute__((ext_vector_type(8))) short bf16x8;

// fp32 -> bf16 (RNE), branchless
__device__ inline unsigned short f2b(float f) {
  uint32_t u = __float_as_uint(f);
  uint32_t r = (u + 0x7fffu + ((u >> 16) & 1u)) >> 16;
  return (unsigned short)r;
}

__device__ inline void async_ld16(const void* g, void* l) {
  __builtin_amdgcn_global_load_lds(
      (const __attribute__((address_space(1))) void*)g,
      (__attribute__((address_space(3))) void*)l, 16, 0, 0);
}

// ======================= bf16 MFMA GEMM: C[M,N] = A[M,K] @ Bt[N,K]^T + bias =======================
// A, Bt bf16 (K contiguous). Cf fp32 out (nullable), Cb bf16 out (nullable).
__global__ __launch_bounds__(256) void gemm_bf16(
    const unsigned short* __restrict__ A, const unsigned short* __restrict__ Bt,
    const float* __restrict__ bias,
    float* __restrict__ Cf, unsigned short* __restrict__ Cb,
    int M, int N, int K, int relu)
{
  __shared__ __align__(16) unsigned short As[128*32];
  __shared__ __align__(16) unsigned short Bs[128*32];
  int tid = threadIdx.x;
  int l = tid & 63;
  int w = tid >> 6;
  int lane15 = l & 15, quad = l >> 4;
  int wm = (w >> 1) * 64, wn = (w & 1) * 64;
  int tileM = blockIdx.y * 128, tileN = blockIdx.x * 128;

  const unsigned short* Ag = A + (size_t)tileM * K;
  const unsigned short* Bg = Bt + (size_t)tileN * K;

  f32x4 acc[4][4];
#pragma unroll
  for (int i = 0; i < 4; i++)
#pragma unroll
    for (int j = 0; j < 4; j++)
      acc[i][j] = (f32x4){0.f, 0.f, 0.f, 0.f};

  for (int k0 = 0; k0 < K; k0 += 32) {
#pragma unroll
    for (int q = 0; q < 2; q++) {
      int f = q * 256 + tid;
      int row = f >> 2, cg = (f & 3) * 8;
      async_ld16(Ag + (size_t)row * K + k0 + cg, &As[f * 8]);
      async_ld16(Bg + (size_t)row * K + k0 + cg, &Bs[f * 8]);
    }
    __syncthreads();
    bf16x8 af[4], bfr[4];
#pragma unroll
    for (int i = 0; i < 4; i++)
      af[i] = *(const bf16x8*)(&As[(wm + i*16 + lane15)*32 + quad*8]);
#pragma unroll
    for (int j = 0; j < 4; j++)
      bfr[j] = *(const bf16x8*)(&Bs[(wn + j*16 + lane15)*32 + quad*8]);
#pragma unroll
    for (int i = 0; i < 4; i++)
#pragma unroll
      for (int j = 0; j < 4; j++)
        acc[i][j] = __builtin_amdgcn_mfma_f32_16x16x32_bf16(af[i], bfr[j], acc[i][j], 0, 0, 0);
    __syncthreads();
  }

#pragma unroll
  for (int i = 0; i < 4; i++) {
    int m0 = tileM + wm + i*16 + quad*4;
#pragma unroll
    for (int j = 0; j < 4; j++) {
      int n_ = tileN + wn + j*16 + lane15;
      float bsv = bias[n_];
#pragma unroll
      for (int r = 0; r < 4; r++) {
        float v = acc[i][j][r] + bsv;
        if (relu) v = fmaxf(v, 0.f);
        size_t idx = (size_t)(m0 + r) * N + n_;
        if (Cf) Cf[idx] = v;
        if (Cb) Cb[idx] = f2b(v);
      }
    }
  }
}

// ======================= weight transpose-convert: Wt[n][k] = bf16(W[k][n]) =======================
__global__ __launch_bounds__(256) void wconv_kernel(
    const float* __restrict__ W, unsigned short* __restrict__ Wt,
    int K, int N, int dstStride)
{
  __shared__ float T[32][33];
  int n0 = blockIdx.x * 32, k0 = blockIdx.y * 32;
  int c = threadIdx.x & 31, r8 = threadIdx.x >> 5;
#pragma unroll
  for (int p = 0; p < 4; p++) {
    int r = p*8 + r8;
    T[r][c] = W[(size_t)(k0 + r)*N + n0 + c];
  }
  __syncthreads();
#pragma unroll
  for (int p = 0; p < 4; p++) {
    int r = p*8 + r8;
    Wt[(size_t)(n0 + r)*dstStride + k0 + c] = f2b(T[c][r]);
  }
}

// ======================= fp32 -> bf16 flat convert =======================
__global__ __launch_bounds__(256) void f2b_kernel(const float* __restrict__ X,
                                                  unsigned short* __restrict__ Y, int n4)
{
  int i = blockIdx.x * 256 + threadIdx.x;
  if (i < n4) {
    float4 v = ((const float4*)X)[i];
    ushort4 o;
    o.x = f2b(v.x); o.y = f2b(v.y); o.z = f2b(v.z); o.w = f2b(v.w);
    ((ushort4*)Y)[i] = o;
  }
}

// ======================= small fp32 copy (bias packing) =======================
__global__ __launch_bounds__(256) void copyf_kernel(const float* __restrict__ s,
                                                    float* __restrict__ d, int n)
{
  int i = blockIdx.x * 256 + threadIdx.x;
  if (i < n) d[i] = s[i];
}

// ======================= residual add + LayerNorm, optional bf16 second output =======================
__global__ __launch_bounds__(256) void add_ln_kernel(
    const float* __restrict__ X, const float* __restrict__ T,
    const float* __restrict__ g, const float* __restrict__ bb,
    float* __restrict__ Y, unsigned short* __restrict__ Yb)
{
  int row = blockIdx.x;
  int tid = threadIdx.x;
  size_t base = (size_t)row * HID;
  float4 xv = ((const float4*)(X + base))[tid];
  float4 tv = ((const float4*)(T + base))[tid];
  float v0 = xv.x + tv.x, v1 = xv.y + tv.y, v2 = xv.z + tv.z, v3 = xv.w + tv.w;
  float s = v0 + v1 + v2 + v3;
  float q = v0*v0 + v1*v1 + v2*v2 + v3*v3;
#pragma unroll
  for (int off = 32; off > 0; off >>= 1) {
    s += __shfl_down(s, off);
    q += __shfl_down(q, off);
  }
  __shared__ float ss[4], qq[4];
  __shared__ float mean_s, rstd_s;
  int wid = tid >> 6, lane = tid & 63;
  if (lane == 0) { ss[wid] = s; qq[wid] = q; }
  __syncthreads();
  if (tid == 0) {
    float S2 = ss[0] + ss[1] + ss[2] + ss[3];
    float Q2 = qq[0] + qq[1] + qq[2] + qq[3];
    float mean = S2 * (1.f / HID);
    float var  = Q2 * (1.f / HID) - mean * mean;
    mean_s = mean;
    rstd_s = rsqrtf(var + EPSV);
  }
  __syncthreads();
  float mean = mean_s, rstd = rstd_s;
  float4 gv = ((const float4*)g)[tid];
  float4 bv = ((const float4*)bb)[tid];
  float4 out;
  out.x = (v0 - mean) * rstd * gv.x + bv.x;
  out.y = (v1 - mean) * rstd * gv.y + bv.y;
  out.z = (v2 - mean) * rstd * gv.z + bv.z;
  out.w = (v3 - mean) * rstd * gv.w + bv.w;
  ((float4*)(Y + base))[tid] = out;
  if (Yb) {
    ushort4 ob;
    ob.x = f2b(out.x); ob.y = f2b(out.y); ob.z = f2b(out.z); ob.w = f2b(out.w);
    ((ushort4*)(Yb + base))[tid] = ob;
  }
}

// ======================= MFMA flash self-attention (bf16 QKV in, bf16 ctx out) =======================
// QKV: [NB*SEQ][3072] bf16 (Q at +0, K at +1024, V at +2048 per row).
// Grid: 1024 blocks (XCD-swizzled); 256 threads = 4 waves, each wave owns 16 Q rows.
// LDS tiles XOR-swizzled in 16B chunks: LDS[row][ch] holds global chunk (ch ^ (row&7))
// so all ds_read_b128 fragment reads are bank-conflict-free.
__global__ __launch_bounds__(256) void flash_attn_mfma(
    const unsigned short* __restrict__ QKV, const int* __restrict__ mask,
    unsigned short* __restrict__ Ctx)
{
  // bijective XCD swizzle: 1024 blocks, 8 XCDs, 128 contiguous wgs per XCD
  // -> each XCD sees 4 consecutive bh, so its K/V panels (2MB) stay L2-resident
  int id = blockIdx.x;
  int wg = (id & 7) * 128 + (id >> 3);
  int bh = wg >> 5;            // 0..31
  int qb = wg & 31;            // 0..31
  int b = bh >> 4, h = bh & 15;
  int q0 = qb * 64;

  const unsigned short* Qb = QKV + (size_t)b * SEQ * 3072 + h * HD;
  const unsigned short* Kb = Qb + 1024;
  const unsigned short* Vb = Qb + 2048;
  const int* mb = mask + b * SEQ;

  __shared__ __align__(16) unsigned short Ks[64 * 64];
  __shared__ __align__(16) unsigned short Vt[64 * 64];   // transposed: [d][k], swizzled
  __shared__ __align__(16) unsigned short Ps[4][16 * 64];

  int tid = threadIdx.x;
  int l = tid & 63, w = tid >> 6;
  int l15 = l & 15, quad = l >> 4;
  int lh = l15 & 7;

  // ---- stage Q tile (64 rows) into Ks via global_load_lds, source pre-swizzled ----
#pragma unroll
  for (int p = 0; p < 2; p++) {
    int f = p * 256 + tid;
    int row = f >> 3, ch = f & 7;
    async_ld16(Qb + (size_t)(q0 + row) * 3072 + ((ch ^ (row & 7)) * 8), &Ks[f * 8]);
  }
  __syncthreads();
  bf16x8 qf[2];
#pragma unroll
  for (int c = 0; c < 2; c++)
    qf[c] = *(const bf16x8*)&Ks[(w * 16 + l15) * 64 + (((c * 4 + quad) ^ lh) * 8)];
  __syncthreads();

  f32x4 oacc[4];
#pragma unroll
  for (int jd = 0; jd < 4; jd++) oacc[jd] = (f32x4){0.f, 0.f, 0.f, 0.f};
  float mrow[4] = {-3e38f, -3e38f, -3e38f, -3e38f};
  float lrow[4] = {0.f, 0.f, 0.f, 0.f};

  unsigned short* Pw = &Ps[w][0];

  for (int k0 = 0; k0 < SEQ; k0 += 64) {
    // ---- stage K tile (async, swizzled source) ----
#pragma unroll
    for (int p = 0; p < 2; p++) {
      int f = p * 256 + tid;
      int row = f >> 3, ch = f & 7;
      async_ld16(Kb + (size_t)(k0 + row) * 3072 + ((ch ^ (row & 7)) * 8), &Ks[f * 8]);
    }
    // ---- stage V tile transposed (k-contiguous rows for PV B-operand) ----
#pragma unroll
    for (int p = 0; p < 2; p++) {
      int f = p * 256 + tid;
      int vk = f >> 3, d0 = (f & 7) * 8;
      bf16x8 vv = *(const bf16x8*)(Vb + (size_t)(k0 + vk) * 3072 + d0);
      int kch = vk >> 3, kin = vk & 7;
#pragma unroll
      for (int j = 0; j < 8; j++)
        Vt[(d0 + j) * 64 + ((kch ^ j) * 8) + kin] = (unsigned short)vv[j];
    }
    __syncthreads();   // drains global_load_lds (vmcnt0) + V transpose writes

    // ---- QK^T: S[16 q][64 k] per wave via 8 MFMAs ----
    f32x4 sacc[4];
#pragma unroll
    for (int j = 0; j < 4; j++) sacc[j] = (f32x4){0.f, 0.f, 0.f, 0.f};
#pragma unroll
    for (int c = 0; c < 2; c++) {
#pragma unroll
      for (int j = 0; j < 4; j++) {
        bf16x8 kf = *(const bf16x8*)&Ks[(j * 16 + l15) * 64 + (((c * 4 + quad) ^ lh) * 8)];
        sacc[j] = __builtin_amdgcn_mfma_f32_16x16x32_bf16(qf[c], kf, sacc[j], 0, 0, 0);
      }
    }

    // ---- scale + mask; wave-parallel online softmax ----
    // C-layout: element (j, r) = S[row = quad*4 + r][col = 16*j + l15]
    float pvv[4][4];
    float tmax[4];
#pragma unroll
    for (int r = 0; r < 4; r++) tmax[r] = -3e38f;
#pragma unroll
    for (int j = 0; j < 4; j++) {
      int mv = mb[k0 + j * 16 + l15];
#pragma unroll
      for (int r = 0; r < 4; r++) {
        float v = sacc[j][r] * ATT_SCALE;
        if (mv == 0) v = -3e38f;
        pvv[j][r] = v;
        tmax[r] = fmaxf(tmax[r], v);
      }
    }
#pragma unroll
    for (int r = 0; r < 4; r++) {
      float t = tmax[r];
#pragma unroll
      for (int off = 1; off < 16; off <<= 1) t = fmaxf(t, __shfl_xor(t, off));
      float nm = fmaxf(mrow[r], t);
      float alpha = __expf(mrow[r] - nm);
      mrow[r] = nm;
      float rs = 0.f;
#pragma unroll
      for (int j = 0; j < 4; j++) {
        float p = __expf(pvv[j][r] - nm);
        pvv[j][r] = p;
        rs += p;
      }
#pragma unroll
      for (int off = 1; off < 16; off <<= 1) rs += __shfl_xor(rs, off);
      lrow[r] = lrow[r] * alpha + rs;
#pragma unroll
      for (int jd = 0; jd < 4; jd++) oacc[jd][r] *= alpha;
    }

    // ---- P (bf16) -> per-wave LDS region, A-fragment layout (swizzled) ----
#pragma unroll
    for (int j = 0; j < 4; j++) {
      int col = j * 16 + l15;
      int ch = col >> 3, ci = col & 7;
#pragma unroll
      for (int r = 0; r < 4; r++) {
        int prow = quad * 4 + r;
        Pw[prow * 64 + ((ch ^ (prow & 7)) * 8) + ci] = f2b(pvv[j][r]);
      }
    }

    // ---- PV: O[16 q][64 d] += P[16][64] @ V[64][64] via 8 MFMAs ----
#pragma unroll
    for (int c = 0; c < 2; c++) {
      bf16x8 ap = *(const bf16x8*)&Pw[l15 * 64 + (((c * 4 + quad) ^ lh) * 8)];
#pragma unroll
      for (int jd = 0; jd < 4; jd++) {
        bf16x8 vf = *(const bf16x8*)&Vt[(jd * 16 + l15) * 64 + (((c * 4 + quad) ^ lh) * 8)];
        oacc[jd] = __builtin_amdgcn_mfma_f32_16x16x32_bf16(ap, vf, oacc[jd], 0, 0, 0);
      }
    }
    __syncthreads();   // protect Ks/Vt before next tile's staging
  }

  // ---- epilogue: normalize + bf16 store ----
  unsigned short* Cb = Ctx + (size_t)(b * SEQ + q0 + w * 16) * HID + h * HD;
  float inv[4];
#pragma unroll
  for (int r = 0; r < 4; r++) inv[r] = 1.f / lrow[r];
#pragma unroll
  for (int jd = 0; jd < 4; jd++)
#pragma unroll
    for (int r = 0; r < 4; r++)
      Cb[(size_t)(quad * 4 + r) * HID + jd * 16 + l15] = f2b(oacc[jd][r] * inv[r]);
}

// ======================= cross-attn scores (strided Q/K) =======================
__global__ __launch_bounds__(256) void attn_scores_kernel(
    const float* __restrict__ Q, int qs, const float* __restrict__ K, int ks,
    const int* __restrict__ mask, float* __restrict__ S)
{
  int bh = blockIdx.z;
  int b = bh >> 4, h = bh & 15;
  int q0 = blockIdx.y * 64, k0 = blockIdx.x * 64;
  const float* Qb = Q + (size_t)b*SEQ*qs + h*HD;
  const float* Kb = K + (size_t)b*SEQ*ks + h*HD;
  const int* mb = mask + b*SEQ;
  __shared__ float Qs[64][65];
  __shared__ float Ks[64][65];
  int tid = threadIdx.x;
  int tx = tid & 15, ty = tid >> 4;
  int lr = tid >> 4, lc = (tid & 15) * 4;
#pragma unroll
  for (int i = 0; i < 4; i++) {
    float4 qv = *(const float4*)(Qb + (size_t)(q0 + lr + 16*i)*qs + lc);
    Qs[lr+16*i][lc]=qv.x; Qs[lr+16*i][lc+1]=qv.y; Qs[lr+16*i][lc+2]=qv.z; Qs[lr+16*i][lc+3]=qv.w;
    float4 kv = *(const float4*)(Kb + (size_t)(k0 + lr + 16*i)*ks + lc);
    Ks[lr+16*i][lc]=kv.x; Ks[lr+16*i][lc+1]=kv.y; Ks[lr+16*i][lc+2]=kv.z; Ks[lr+16*i][lc+3]=kv.w;
  }
  __syncthreads();
  float acc[4][4] = {};
#pragma unroll 8
  for (int kk = 0; kk < HD; kk++) {
    float a[4], bv[4];
#pragma unroll
    for (int i = 0; i < 4; i++) a[i] = Qs[ty*4+i][kk];
#pragma unroll
    for (int j = 0; j < 4; j++) bv[j] = Ks[tx*4+j][kk];
#pragma unroll
    for (int i = 0; i < 4; i++)
#pragma unroll
      for (int j = 0; j < 4; j++)
        acc[i][j] = fmaf(a[i], bv[j], acc[i][j]);
  }
  size_t base = (size_t)bh * SEQ * SEQ;
#pragma unroll
  for (int i = 0; i < 4; i++) {
    float4 ov;
    float* op = &ov.x;
#pragma unroll
    for (int j = 0; j < 4; j++) {
      float v = acc[i][j] * ATT_SCALE;
      if (mb[k0 + tx*4 + j] == 0) v = -INFINITY;
      op[j] = v;
    }
    *(float4*)(S + base + (size_t)(q0 + ty*4 + i)*SEQ + k0 + tx*4) = ov;
  }
}

// ======================= row softmax over 2048 (in place) =======================
__global__ __launch_bounds__(256) void softmax_kernel(float* __restrict__ S)
{
  size_t row = blockIdx.x;
  float* p = S + row * (size_t)SEQ;
  int tid = threadIdx.x;
  float4 a = ((const float4*)p)[tid];
  float4 b = ((const float4*)p)[tid + 256];
  float m = fmaxf(fmaxf(fmaxf(a.x, a.y), fmaxf(a.z, a.w)),
                  fmaxf(fmaxf(b.x, b.y), fmaxf(b.z, b.w)));
#pragma unroll
  for (int off = 32; off > 0; off >>= 1) m = fmaxf(m, __shfl_down(m, off));
  __shared__ float red[4];
  __shared__ float bmax, bsum;
  int wid = tid >> 6, lane = tid & 63;
  if (lane == 0) red[wid] = m;
  __syncthreads();
  if (tid == 0) bmax = fmaxf(fmaxf(red[0], red[1]), fmaxf(red[2], red[3]));
  __syncthreads();
  m = bmax;
  a.x = __expf(a.x - m); a.y = __expf(a.y - m); a.z = __expf(a.z - m); a.w = __expf(a.w - m);
  b.x = __expf(b.x - m); b.y = __expf(b.y - m); b.z = __expf(b.z - m); b.w = __expf(b.w - m);
  float s = a.x + a.y + a.z + a.w + b.x + b.y + b.z + b.w;
#pragma unroll
  for (int off = 32; off > 0; off >>= 1) s += __shfl_down(s, off);
  if (lane == 0) red[wid] = s;
  __syncthreads();
  if (tid == 0) bsum = red[0] + red[1] + red[2] + red[3];
  __syncthreads();
  float inv = 1.f / bsum;
  a.x *= inv; a.y *= inv; a.z *= inv; a.w *= inv;
  b.x *= inv; b.y *= inv; b.z *= inv; b.w *= inv;
  ((float4*)p)[tid] = a;
  ((float4*)p)[tid + 256] = b;
}

// ======================= PV (strided V, bf16 ctx out) =======================
__global__ __launch_bounds__(256) void attn_pv_kernel(
    const float* __restrict__ P, const float* __restrict__ V, int vs,
    unsigned short* __restrict__ Ctx)
{
  int bh = blockIdx.y;
  int b = bh >> 4, h = bh & 15;
  int q0 = blockIdx.x * 64;
  const float* Pb = P + (size_t)bh * SEQ * SEQ;
  const float* Vb = V + (size_t)b * SEQ * vs + h * HD;
  unsigned short* Cb = Ctx + (size_t)b * SEQ * HID + h * HD;
  __shared__ float Ps[64][17];
  __shared__ float Vs[16][65];
  int tid = threadIdx.x;
  int tx = tid & 15, ty = tid >> 4;
  int pk = tid & 15, pq = tid >> 4;
  int vd = tid & 63, vk = tid >> 6;
  float acc[4][4] = {};
  for (int k0 = 0; k0 < SEQ; k0 += 16) {
#pragma unroll
    for (int i = 0; i < 4; i++)
      Ps[pq + 16*i][pk] = Pb[(size_t)(q0 + pq + 16*i)*SEQ + k0 + pk];
#pragma unroll
    for (int i = 0; i < 4; i++)
      Vs[vk + 4*i][vd] = Vb[(size_t)(k0 + vk + 4*i)*vs + vd];
    __syncthreads();
#pragma unroll
    for (int kk = 0; kk < 16; kk++) {
      float a[4], bv[4];
#pragma unroll
      for (int i = 0; i < 4; i++) a[i] = Ps[ty*4+i][kk];
#pragma unroll
      for (int j = 0; j < 4; j++) bv[j] = Vs[kk][tx*4+j];
#pragma unroll
      for (int i = 0; i < 4; i++)
#pragma unroll
        for (int j = 0; j < 4; j++)
          acc[i][j] = fmaf(a[i], bv[j], acc[i][j]);
    }
    __syncthreads();
  }
#pragma unroll
  for (int i = 0; i < 4; i++) {
    ushort4 ov;
    ov.x = f2b(acc[i][0]); ov.y = f2b(acc[i][1]);
    ov.z = f2b(acc[i][2]); ov.w = f2b(acc[i][3]);
    *(ushort4*)(Cb + (size_t)(q0 + ty*4 + i)*HID + tx*4) = ov;
  }
}

// ======================= host launch =======================
extern "C" void kernel_launch(void* const* d_in, const int* in_sizes, int n_in,
                              void* d_out, int out_size, void* d_ws, size_t ws_size,
                              hipStream_t stream)
{
  const float* tgt  = (const float*)d_in[0];
  const float* enc  = (const float*)d_in[1];
  const int* tmask  = (const int*)d_in[2];
  const int* smask  = (const int*)d_in[3];
  const float* sa_wq = (const float*)d_in[4],  *sa_bq = (const float*)d_in[5];
  const float* sa_wk = (const float*)d_in[6],  *sa_bk = (const float*)d_in[7];
  const float* sa_wv = (const float*)d_in[8],  *sa_bv = (const float*)d_in[9];
  const float* sa_wo = (const float*)d_in[10], *sa_bo = (const float*)d_in[11];
  const float* ea_wq = (const float*)d_in[12], *ea_bq = (const float*)d_in[13];
  const float* ea_wk = (const float*)d_in[14], *ea_bk = (const float*)d_in[15];
  const float* ea_wv = (const float*)d_in[16], *ea_bv = (const float*)d_in[17];
  const float* ea_wo = (const float*)d_in[18], *ea_bo = (const float*)d_in[19];
  const float* ffn_w1 = (const float*)d_in[20], *ffn_b1 = (const float*)d_in[21];
  const float* ffn_w2 = (const float*)d_in[22], *ffn_b2 = (const float*)d_in[23];
  const float* ln1_g = (const float*)d_in[24], *ln1_b = (const float*)d_in[25];
  const float* ln2_g = (const float*)d_in[26], *ln2_b = (const float*)d_in[27];
  const float* ln3_g = (const float*)d_in[28], *ln3_b = (const float*)d_in[29];

  const size_t NBUF = (size_t)NB * SEQ * HID;  // 4 Mi elements
  float* out_tgt  = (float*)d_out;
  float* out_attn = (float*)d_out + NBUF;

  char* ws = (char*)d_ws;
  // R0: 0..48MB — QKVb(self, bf16 24MB) -> KVc+Qc(cross) -> Hb(ffn hidden) / x2b
  unsigned short* QKVb = (unsigned short*)(ws);         // [4096,3072] bf16, 24MB
  float*          KVc  = (float*)(ws);                  // [4096,2048] fp32, 32MB
  float*          Qc   = (float*)(ws + 32*MB);          // [4096,1024] fp32, 16MB
  unsigned short* Hb   = (unsigned short*)(ws);         // [4096,4096] bf16, 32MB
  unsigned short* x2b  = (unsigned short*)(ws + 32*MB); // 8MB (after Qc dead)
  float*          T    = (float*)(ws + 48*MB);          // 16MB
  float*          x1   = (float*)(ws + 64*MB);          // 16MB
  float*          x2   = (float*)(ws + 80*MB);          // 16MB (overlays tgtb/encb)
  unsigned short* tgtb = (unsigned short*)(ws + 80*MB); // 8MB
  unsigned short* encb = (unsigned short*)(ws + 88*MB); // 8MB
  unsigned short* ctxb = (unsigned short*)(ws + 96*MB); // 8MB (also x1b)
  unsigned short* x1b  = ctxb;
  unsigned short* qkv_t  = (unsigned short*)(ws + 104*MB); // [3072,1024] 6MB
  unsigned short* sawo_t = (unsigned short*)(ws + 110*MB); // 2MB
  unsigned short* eaq_t  = (unsigned short*)(ws + 112*MB); // 2MB
  unsigned short* eakv_t = (unsigned short*)(ws + 114*MB); // [2048,1024] 4MB
  unsigned short* eawo_t = (unsigned short*)(ws + 118*MB); // 2MB
  unsigned short* w1t    = (unsigned short*)(ws + 120*MB); // [4096,1024] 8MB
  unsigned short* w2t    = (unsigned short*)(ws + 128*MB); // [1024,4096] 8MB
  float*          b_qkv  = (float*)(ws + 136*MB);          // 3072
  float*          b_kv   = (float*)(ws + 136*MB + 16384);  // 2048

  const int M = NB * SEQ;  // 4096
  dim3 blk(256);
  dim3 g32(32, 32);

  // ---- prep: weight transpose-convert + bias pack + activation convert ----
  wconv_kernel<<<g32, blk, 0, stream>>>(sa_wq, qkv_t,                 HID, HID, HID);
  wconv_kernel<<<g32, blk, 0, stream>>>(sa_wk, qkv_t + 1024*1024,     HID, HID, HID);
  wconv_kernel<<<g32, blk, 0, stream>>>(sa_wv, qkv_t + 2048*1024,     HID, HID, HID);
  wconv_kernel<<<g32, blk, 0, stream>>>(sa_wo, sawo_t,                HID, HID, HID);
  wconv_kernel<<<g32, blk, 0, stream>>>(ea_wq, eaq_t,                 HID, HID, HID);
  wconv_kernel<<<g32, blk, 0, stream>>>(ea_wk, eakv_t,                HID, HID, HID);
  wconv_kernel<<<g32, blk, 0, stream>>>(ea_wv, eakv_t + 1024*1024,    HID, HID, HID);
  wconv_kernel<<<g32, blk, 0, stream>>>(ea_wo, eawo_t,                HID, HID, HID);
  wconv_kernel<<<dim3(128, 32), blk, 0, stream>>>(ffn_w1, w1t, HID, PF, HID);
  wconv_kernel<<<dim3(32, 128), blk, 0, stream>>>(ffn_w2, w2t, PF, HID, PF);
  copyf_kernel<<<4, blk, 0, stream>>>(sa_bq, b_qkv, 1024);
  copyf_kernel<<<4, blk, 0, stream>>>(sa_bk, b_qkv + 1024, 1024);
  copyf_kernel<<<4, blk, 0, stream>>>(sa_bv, b_qkv + 2048, 1024);
  copyf_kernel<<<4, blk, 0, stream>>>(ea_bk, b_kv, 1024);
  copyf_kernel<<<4, blk, 0, stream>>>(ea_bv, b_kv + 1024, 1024);
  f2b_kernel<<<4096, blk, 0, stream>>>(tgt, tgtb, 1024*1024);
  f2b_kernel<<<4096, blk, 0, stream>>>(enc, encb, 1024*1024);

  // ---- self-attention (bf16 QKV + MFMA flash) ----
  gemm_bf16<<<dim3(3072/128, M/128), blk, 0, stream>>>(tgtb, qkv_t, b_qkv, nullptr, QKVb, M, 3072, HID, 0);
  flash_attn_mfma<<<dim3(1024), blk, 0, stream>>>(QKVb, tmask, ctxb);
  gemm_bf16<<<dim3(HID/128, M/128), blk, 0, stream>>>(ctxb, sawo_t, sa_bo, T, nullptr, M, HID, HID, 0);
  add_ln_kernel<<<M, blk, 0, stream>>>(tgt, T, ln1_g, ln1_b, x1, x1b);

  // ---- cross-attention ----
  gemm_bf16<<<dim3(2048/128, M/128), blk, 0, stream>>>(encb, eakv_t, b_kv, KVc, nullptr, M, 2048, HID, 0);
  gemm_bf16<<<dim3(HID/128, M/128), blk, 0, stream>>>(x1b, eaq_t, ea_bq, Qc, nullptr, M, HID, HID, 0);
  attn_scores_kernel<<<dim3(SEQ/64, SEQ/64, NB*HEADS), blk, 0, stream>>>(Qc, 1024, KVc, 2048, smask, out_attn);
  softmax_kernel<<<NB*HEADS*SEQ, blk, 0, stream>>>(out_attn);
  attn_pv_kernel<<<dim3(SEQ/64, NB*HEADS), blk, 0, stream>>>(out_attn, KVc + 1024, 2048, ctxb);
  gemm_bf16<<<dim3(HID/128, M/128), blk, 0, stream>>>(ctxb, eawo_t, ea_bo, T, nullptr, M, HID, HID, 0);
  add_ln_kernel<<<M, blk, 0, stream>>>(x1, T, ln2_g, ln2_b, x2, x2b);

  // ---- FFN ----
  gemm_bf16<<<dim3(PF/128, M/128), blk, 0, stream>>>(x2b, w1t, ffn_b1, nullptr, Hb, M, PF, HID, 1);
  gemm_bf16<<<dim3(HID/128, M/128), blk, 0, stream>>>(Hb, w2t, ffn_b2, T, nullptr, M, HID, PF, 0);
  add_ln_kernel<<<M, blk, 0, stream>>>(x2, T, ln3_g, ln3_b, out_tgt, nullptr);
}

// Round 3
// 1421.127 us; speedup vs baseline: 1.9473x; 1.4066x over previous
//
#include <hip/hip_runtime.h>
#include <cstddef>
#include <cstdint>

#define NB 2
#define SEQ 2048
#define HID 1024
#define HEADS 16
#define HD 64
#define PF 4096
#define EPSV 1e-5f
#define ATT_SCALE 0.125f   // 1/sqrt(64)
#define MB (1024ull*1024ull)

typedef __attribute__((ext_vector_type(4))) float f32x4;
typedef __attribute__((ext_vector_type(8))) short bf16x8;

// fp32 -> bf16 (RNE), branchless
__device__ inline unsigned short f2b(float f) {
  uint32_t u = __float_as_uint(f);
  uint32_t r = (u + 0x7fffu + ((u >> 16) & 1u)) >> 16;
  return (unsigned short)r;
}

__device__ inline void async_ld16(const void* g, void* l) {
  __builtin_amdgcn_global_load_lds(
      (const __attribute__((address_space(1))) void*)g,
      (__attribute__((address_space(3))) void*)l, 16, 0, 0);
}

// ======================= bf16 MFMA GEMM: C[M,N] = A[M,K] @ Bt[N,K]^T + bias =======================
// A, Bt bf16 (K contiguous). Cf fp32 out (nullable), Cb bf16 out (nullable).
__global__ __launch_bounds__(256) void gemm_bf16(
    const unsigned short* __restrict__ A, const unsigned short* __restrict__ Bt,
    const float* __restrict__ bias,
    float* __restrict__ Cf, unsigned short* __restrict__ Cb,
    int M, int N, int K, int relu)
{
  __shared__ __align__(16) unsigned short As[128*32];
  __shared__ __align__(16) unsigned short Bs[128*32];
  int tid = threadIdx.x;
  int l = tid & 63;
  int w = tid >> 6;
  int lane15 = l & 15, quad = l >> 4;
  int wm = (w >> 1) * 64, wn = (w & 1) * 64;
  int tileM = blockIdx.y * 128, tileN = blockIdx.x * 128;

  const unsigned short* Ag = A + (size_t)tileM * K;
  const unsigned short* Bg = Bt + (size_t)tileN * K;

  f32x4 acc[4][4];
#pragma unroll
  for (int i = 0; i < 4; i++)
#pragma unroll
    for (int j = 0; j < 4; j++)
      acc[i][j] = (f32x4){0.f, 0.f, 0.f, 0.f};

  for (int k0 = 0; k0 < K; k0 += 32) {
#pragma unroll
    for (int q = 0; q < 2; q++) {
      int f = q * 256 + tid;
      int row = f >> 2, cg = (f & 3) * 8;
      async_ld16(Ag + (size_t)row * K + k0 + cg, &As[f * 8]);
      async_ld16(Bg + (size_t)row * K + k0 + cg, &Bs[f * 8]);
    }
    __syncthreads();
    bf16x8 af[4], bfr[4];
#pragma unroll
    for (int i = 0; i < 4; i++)
      af[i] = *(const bf16x8*)(&As[(wm + i*16 + lane15)*32 + quad*8]);
#pragma unroll
    for (int j = 0; j < 4; j++)
      bfr[j] = *(const bf16x8*)(&Bs[(wn + j*16 + lane15)*32 + quad*8]);
#pragma unroll
    for (int i = 0; i < 4; i++)
#pragma unroll
      for (int j = 0; j < 4; j++)
        acc[i][j] = __builtin_amdgcn_mfma_f32_16x16x32_bf16(af[i], bfr[j], acc[i][j], 0, 0, 0);
    __syncthreads();
  }

#pragma unroll
  for (int i = 0; i < 4; i++) {
    int m0 = tileM + wm + i*16 + quad*4;
#pragma unroll
    for (int j = 0; j < 4; j++) {
      int n_ = tileN + wn + j*16 + lane15;
      float bsv = bias[n_];
#pragma unroll
      for (int r = 0; r < 4; r++) {
        float v = acc[i][j][r] + bsv;
        if (relu) v = fmaxf(v, 0.f);
        size_t idx = (size_t)(m0 + r) * N + n_;
        if (Cf) Cf[idx] = v;
        if (Cb) Cb[idx] = f2b(v);
      }
    }
  }
}

// ======================= weight transpose-convert: Wt[n][k] = bf16(W[k][n]) =======================
__global__ __launch_bounds__(256) void wconv_kernel(
    const float* __restrict__ W, unsigned short* __restrict__ Wt,
    int K, int N, int dstStride)
{
  __shared__ float T[32][33];
  int n0 = blockIdx.x * 32, k0 = blockIdx.y * 32;
  int c = threadIdx.x & 31, r8 = threadIdx.x >> 5;
#pragma unroll
  for (int p = 0; p < 4; p++) {
    int r = p*8 + r8;
    T[r][c] = W[(size_t)(k0 + r)*N + n0 + c];
  }
  __syncthreads();
#pragma unroll
  for (int p = 0; p < 4; p++) {
    int r = p*8 + r8;
    Wt[(size_t)(n0 + r)*dstStride + k0 + c] = f2b(T[c][r]);
  }
}

// ======================= fp32 -> bf16 flat convert =======================
__global__ __launch_bounds__(256) void f2b_kernel(const float* __restrict__ X,
                                                  unsigned short* __restrict__ Y, int n4)
{
  int i = blockIdx.x * 256 + threadIdx.x;
  if (i < n4) {
    float4 v = ((const float4*)X)[i];
    ushort4 o;
    o.x = f2b(v.x); o.y = f2b(v.y); o.z = f2b(v.z); o.w = f2b(v.w);
    ((ushort4*)Y)[i] = o;
  }
}

// ======================= small fp32 copy (bias packing) =======================
__global__ __launch_bounds__(256) void copyf_kernel(const float* __restrict__ s,
                                                    float* __restrict__ d, int n)
{
  int i = blockIdx.x * 256 + threadIdx.x;
  if (i < n) d[i] = s[i];
}

// ======================= residual add + LayerNorm, optional bf16 second output =======================
__global__ __launch_bounds__(256) void add_ln_kernel(
    const float* __restrict__ X, const float* __restrict__ T,
    const float* __restrict__ g, const float* __restrict__ bb,
    float* __restrict__ Y, unsigned short* __restrict__ Yb)
{
  int row = blockIdx.x;
  int tid = threadIdx.x;
  size_t base = (size_t)row * HID;
  float4 xv = ((const float4*)(X + base))[tid];
  float4 tv = ((const float4*)(T + base))[tid];
  float v0 = xv.x + tv.x, v1 = xv.y + tv.y, v2 = xv.z + tv.z, v3 = xv.w + tv.w;
  float s = v0 + v1 + v2 + v3;
  float q = v0*v0 + v1*v1 + v2*v2 + v3*v3;
#pragma unroll
  for (int off = 32; off > 0; off >>= 1) {
    s += __shfl_down(s, off);
    q += __shfl_down(q, off);
  }
  __shared__ float ss[4], qq[4];
  __shared__ float mean_s, rstd_s;
  int wid = tid >> 6, lane = tid & 63;
  if (lane == 0) { ss[wid] = s; qq[wid] = q; }
  __syncthreads();
  if (tid == 0) {
    float S2 = ss[0] + ss[1] + ss[2] + ss[3];
    float Q2 = qq[0] + qq[1] + qq[2] + qq[3];
    float mean = S2 * (1.f / HID);
    float var  = Q2 * (1.f / HID) - mean * mean;
    mean_s = mean;
    rstd_s = rsqrtf(var + EPSV);
  }
  __syncthreads();
  float mean = mean_s, rstd = rstd_s;
  float4 gv = ((const float4*)g)[tid];
  float4 bv = ((const float4*)bb)[tid];
  float4 out;
  out.x = (v0 - mean) * rstd * gv.x + bv.x;
  out.y = (v1 - mean) * rstd * gv.y + bv.y;
  out.z = (v2 - mean) * rstd * gv.z + bv.z;
  out.w = (v3 - mean) * rstd * gv.w + bv.w;
  ((float4*)(Y + base))[tid] = out;
  if (Yb) {
    ushort4 ob;
    ob.x = f2b(out.x); ob.y = f2b(out.y); ob.z = f2b(out.z); ob.w = f2b(out.w);
    ((ushort4*)(Yb + base))[tid] = ob;
  }
}

// ======================= MFMA flash self-attention (bf16 QKV in, bf16 ctx out) =======================
// QKV: [NB*SEQ][3072] bf16 (Q at +0, K at +1024, V at +2048 per row).
__global__ __launch_bounds__(256) void flash_attn_mfma(
    const unsigned short* __restrict__ QKV, const int* __restrict__ mask,
    unsigned short* __restrict__ Ctx)
{
  // bijective XCD swizzle: 1024 blocks, 8 XCDs, 128 contiguous wgs per XCD
  int id = blockIdx.x;
  int wg = (id & 7) * 128 + (id >> 3);
  int bh = wg >> 5;            // 0..31
  int qb = wg & 31;            // 0..31
  int b = bh >> 4, h = bh & 15;
  int q0 = qb * 64;

  const unsigned short* Qb = QKV + (size_t)b * SEQ * 3072 + h * HD;
  const unsigned short* Kb = Qb + 1024;
  const unsigned short* Vb = Qb + 2048;
  const int* mb = mask + b * SEQ;

  __shared__ __align__(16) unsigned short Ks[64 * 64];
  __shared__ __align__(16) unsigned short Vt[64 * 64];   // transposed: [d][k], swizzled
  __shared__ __align__(16) unsigned short Ps[4][16 * 64];

  int tid = threadIdx.x;
  int l = tid & 63, w = tid >> 6;
  int l15 = l & 15, quad = l >> 4;
  int lh = l15 & 7;

  // ---- stage Q tile (64 rows) into Ks via global_load_lds, source pre-swizzled ----
#pragma unroll
  for (int p = 0; p < 2; p++) {
    int f = p * 256 + tid;
    int row = f >> 3, ch = f & 7;
    async_ld16(Qb + (size_t)(q0 + row) * 3072 + ((ch ^ (row & 7)) * 8), &Ks[f * 8]);
  }
  __syncthreads();
  bf16x8 qf[2];
#pragma unroll
  for (int c = 0; c < 2; c++)
    qf[c] = *(const bf16x8*)&Ks[(w * 16 + l15) * 64 + (((c * 4 + quad) ^ lh) * 8)];
  __syncthreads();

  f32x4 oacc[4];
#pragma unroll
  for (int jd = 0; jd < 4; jd++) oacc[jd] = (f32x4){0.f, 0.f, 0.f, 0.f};
  float mrow[4] = {-3e38f, -3e38f, -3e38f, -3e38f};
  float lrow[4] = {0.f, 0.f, 0.f, 0.f};

  unsigned short* Pw = &Ps[w][0];

  for (int k0 = 0; k0 < SEQ; k0 += 64) {
#pragma unroll
    for (int p = 0; p < 2; p++) {
      int f = p * 256 + tid;
      int row = f >> 3, ch = f & 7;
      async_ld16(Kb + (size_t)(k0 + row) * 3072 + ((ch ^ (row & 7)) * 8), &Ks[f * 8]);
    }
#pragma unroll
    for (int p = 0; p < 2; p++) {
      int f = p * 256 + tid;
      int vk = f >> 3, d0 = (f & 7) * 8;
      bf16x8 vv = *(const bf16x8*)(Vb + (size_t)(k0 + vk) * 3072 + d0);
      int kch = vk >> 3, kin = vk & 7;
#pragma unroll
      for (int j = 0; j < 8; j++)
        Vt[(d0 + j) * 64 + ((kch ^ j) * 8) + kin] = (unsigned short)vv[j];
    }
    __syncthreads();

    f32x4 sacc[4];
#pragma unroll
    for (int j = 0; j < 4; j++) sacc[j] = (f32x4){0.f, 0.f, 0.f, 0.f};
#pragma unroll
    for (int c = 0; c < 2; c++) {
#pragma unroll
      for (int j = 0; j < 4; j++) {
        bf16x8 kf = *(const bf16x8*)&Ks[(j * 16 + l15) * 64 + (((c * 4 + quad) ^ lh) * 8)];
        sacc[j] = __builtin_amdgcn_mfma_f32_16x16x32_bf16(qf[c], kf, sacc[j], 0, 0, 0);
      }
    }

    float pvv[4][4];
    float tmax[4];
#pragma unroll
    for (int r = 0; r < 4; r++) tmax[r] = -3e38f;
#pragma unroll
    for (int j = 0; j < 4; j++) {
      int mv = mb[k0 + j * 16 + l15];
#pragma unroll
      for (int r = 0; r < 4; r++) {
        float v = sacc[j][r] * ATT_SCALE;
        if (mv == 0) v = -3e38f;
        pvv[j][r] = v;
        tmax[r] = fmaxf(tmax[r], v);
      }
    }
#pragma unroll
    for (int r = 0; r < 4; r++) {
      float t = tmax[r];
#pragma unroll
      for (int off = 1; off < 16; off <<= 1) t = fmaxf(t, __shfl_xor(t, off));
      float nm = fmaxf(mrow[r], t);
      float alpha = __expf(mrow[r] - nm);
      mrow[r] = nm;
      float rs = 0.f;
#pragma unroll
      for (int j = 0; j < 4; j++) {
        float p = __expf(pvv[j][r] - nm);
        pvv[j][r] = p;
        rs += p;
      }
#pragma unroll
      for (int off = 1; off < 16; off <<= 1) rs += __shfl_xor(rs, off);
      lrow[r] = lrow[r] * alpha + rs;
#pragma unroll
      for (int jd = 0; jd < 4; jd++) oacc[jd][r] *= alpha;
    }

#pragma unroll
    for (int j = 0; j < 4; j++) {
      int col = j * 16 + l15;
      int ch = col >> 3, ci = col & 7;
#pragma unroll
      for (int r = 0; r < 4; r++) {
        int prow = quad * 4 + r;
        Pw[prow * 64 + ((ch ^ (prow & 7)) * 8) + ci] = f2b(pvv[j][r]);
      }
    }

#pragma unroll
    for (int c = 0; c < 2; c++) {
      bf16x8 ap = *(const bf16x8*)&Pw[l15 * 64 + (((c * 4 + quad) ^ lh) * 8)];
#pragma unroll
      for (int jd = 0; jd < 4; jd++) {
        bf16x8 vf = *(const bf16x8*)&Vt[(jd * 16 + l15) * 64 + (((c * 4 + quad) ^ lh) * 8)];
        oacc[jd] = __builtin_amdgcn_mfma_f32_16x16x32_bf16(ap, vf, oacc[jd], 0, 0, 0);
      }
    }
    __syncthreads();
  }

  unsigned short* Cb = Ctx + (size_t)(b * SEQ + q0 + w * 16) * HID + h * HD;
  float inv[4];
#pragma unroll
  for (int r = 0; r < 4; r++) inv[r] = 1.f / lrow[r];
#pragma unroll
  for (int jd = 0; jd < 4; jd++)
#pragma unroll
    for (int r = 0; r < 4; r++)
      Cb[(size_t)(quad * 4 + r) * HID + jd * 16 + l15] = f2b(oacc[jd][r] * inv[r]);
}

// ======================= fused cross-attention (bf16 Q/KV in, fp32 P out, bf16 ctx out) =======================
// Qb_: [NB*SEQ][1024] bf16. KVb_: [NB*SEQ][2048] bf16 (K at +0, V at +1024 per row).
// Two-phase exact softmax: phase 1 computes row max m and sum l via online reduction;
// phase 2 recomputes S, writes normalized P (fp32, coalesced via LDS) and accumulates PV.
// Grid: 1024 blocks (XCD-swizzled), 256 threads = 4 waves, each wave owns 16 q-rows.
__global__ __launch_bounds__(256) void cross_attn_fused(
    const unsigned short* __restrict__ Qb_, const unsigned short* __restrict__ KVb_,
    const int* __restrict__ mask, float* __restrict__ P, unsigned short* __restrict__ Ctx)
{
  int id = blockIdx.x;
  int wg = (id & 7) * 128 + (id >> 3);
  int bh = wg >> 5, qb = wg & 31;
  int b = bh >> 4, h = bh & 15;
  int q0 = qb * 64;

  const unsigned short* Qp = Qb_ + (size_t)b * SEQ * HID + h * HD;
  const unsigned short* Kp = KVb_ + (size_t)b * SEQ * 2048 + h * HD;
  const unsigned short* Vp = Kp + 1024;
  const int* mb = mask + b * SEQ;
  float* Pb = P + (size_t)bh * SEQ * SEQ + (size_t)q0 * SEQ;

  __shared__ __align__(16) unsigned short Ks[64 * 64];
  __shared__ __align__(16) unsigned short Vt[64 * 64];
  __shared__ float Ss[64][66];

  int tid = threadIdx.x;
  int l = tid & 63, w = tid >> 6;
  int l15 = l & 15, quad = l >> 4;
  int lh = l15 & 7;

  // ---- stage Q tile once (through Ks buffer), keep in registers ----
#pragma unroll
  for (int p = 0; p < 2; p++) {
    int f = p * 256 + tid;
    int row = f >> 3, ch = f & 7;
    async_ld16(Qp + (size_t)(q0 + row) * HID + ((ch ^ (row & 7)) * 8), &Ks[f * 8]);
  }
  __syncthreads();
  bf16x8 qf[2];
#pragma unroll
  for (int c = 0; c < 2; c++)
    qf[c] = *(const bf16x8*)&Ks[(w * 16 + l15) * 64 + (((c * 4 + quad) ^ lh) * 8)];
  __syncthreads();

  float mrow[4] = {-3e38f, -3e38f, -3e38f, -3e38f};
  float lrow[4] = {0.f, 0.f, 0.f, 0.f};

  // ================= phase 1: exact row max + sum =================
  for (int k0 = 0; k0 < SEQ; k0 += 64) {
#pragma unroll
    for (int p = 0; p < 2; p++) {
      int f = p * 256 + tid;
      int row = f >> 3, ch = f & 7;
      async_ld16(Kp + (size_t)(k0 + row) * 2048 + ((ch ^ (row & 7)) * 8), &Ks[f * 8]);
    }
    __syncthreads();

    f32x4 sacc[4];
#pragma unroll
    for (int j = 0; j < 4; j++) sacc[j] = (f32x4){0.f, 0.f, 0.f, 0.f};
#pragma unroll
    for (int c = 0; c < 2; c++) {
#pragma unroll
      for (int j = 0; j < 4; j++) {
        bf16x8 kf = *(const bf16x8*)&Ks[(j * 16 + l15) * 64 + (((c * 4 + quad) ^ lh) * 8)];
        sacc[j] = __builtin_amdgcn_mfma_f32_16x16x32_bf16(qf[c], kf, sacc[j], 0, 0, 0);
      }
    }

    float pvv[4][4];
    float tmax[4];
#pragma unroll
    for (int r = 0; r < 4; r++) tmax[r] = -3e38f;
#pragma unroll
    for (int j = 0; j < 4; j++) {
      int mv = mb[k0 + j * 16 + l15];
#pragma unroll
      for (int r = 0; r < 4; r++) {
        float v = sacc[j][r] * ATT_SCALE;
        if (mv == 0) v = -3e38f;
        pvv[j][r] = v;
        tmax[r] = fmaxf(tmax[r], v);
      }
    }
#pragma unroll
    for (int r = 0; r < 4; r++) {
      float t = tmax[r];
#pragma unroll
      for (int off = 1; off < 16; off <<= 1) t = fmaxf(t, __shfl_xor(t, off));
      float nm = fmaxf(mrow[r], t);
      float alpha = __expf(mrow[r] - nm);
      mrow[r] = nm;
      float rs = 0.f;
#pragma unroll
      for (int j = 0; j < 4; j++) rs += __expf(pvv[j][r] - nm);
#pragma unroll
      for (int off = 1; off < 16; off <<= 1) rs += __shfl_xor(rs, off);
      lrow[r] = lrow[r] * alpha + rs;
    }
    __syncthreads();
  }

  float invl[4];
#pragma unroll
  for (int r = 0; r < 4; r++) invl[r] = 1.f / lrow[r];

  f32x4 oacc[4];
#pragma unroll
  for (int jd = 0; jd < 4; jd++) oacc[jd] = (f32x4){0.f, 0.f, 0.f, 0.f};

  // ================= phase 2: normalized P write + PV =================
  for (int k0 = 0; k0 < SEQ; k0 += 64) {
#pragma unroll
    for (int p = 0; p < 2; p++) {
      int f = p * 256 + tid;
      int row = f >> 3, ch = f & 7;
      async_ld16(Kp + (size_t)(k0 + row) * 2048 + ((ch ^ (row & 7)) * 8), &Ks[f * 8]);
    }
#pragma unroll
    for (int p = 0; p < 2; p++) {
      int f = p * 256 + tid;
      int vk = f >> 3, d0 = (f & 7) * 8;
      bf16x8 vv = *(const bf16x8*)(Vp + (size_t)(k0 + vk) * 2048 + d0);
      int kch = vk >> 3, kin = vk & 7;
#pragma unroll
      for (int j = 0; j < 8; j++)
        Vt[(d0 + j) * 64 + ((kch ^ j) * 8) + kin] = (unsigned short)vv[j];
    }
    __syncthreads();

    f32x4 sacc[4];
#pragma unroll
    for (int j = 0; j < 4; j++) sacc[j] = (f32x4){0.f, 0.f, 0.f, 0.f};
#pragma unroll
    for (int c = 0; c < 2; c++) {
#pragma unroll
      for (int j = 0; j < 4; j++) {
        bf16x8 kf = *(const bf16x8*)&Ks[(j * 16 + l15) * 64 + (((c * 4 + quad) ^ lh) * 8)];
        sacc[j] = __builtin_amdgcn_mfma_f32_16x16x32_bf16(qf[c], kf, sacc[j], 0, 0, 0);
      }
    }

    // normalized P -> Ss (block-wide 64x66 fp32)
#pragma unroll
    for (int j = 0; j < 4; j++) {
      int mv = mb[k0 + j * 16 + l15];
#pragma unroll
      for (int r = 0; r < 4; r++) {
        float v = sacc[j][r] * ATT_SCALE;
        if (mv == 0) v = -3e38f;
        float p = __expf(v - mrow[r]) * invl[r];
        Ss[w * 16 + quad * 4 + r][j * 16 + l15] = p;
      }
    }
    __syncthreads();

    // coalesced global write of P tile (64 rows x 64 cols, 256B per 16 lanes)
#pragma unroll
    for (int i = 0; i < 4; i++) {
      int row = i * 16 + (tid >> 4);
      int c4 = (tid & 15) * 4;
      *(float4*)(Pb + (size_t)row * SEQ + k0 + c4) = *(const float4*)&Ss[row][c4];
    }

    // PV: A-fragment from Ss (fp32 -> bf16), B-fragment from Vt
#pragma unroll
    for (int c = 0; c < 2; c++) {
      bf16x8 ap;
      const float* sp = &Ss[w * 16 + l15][c * 32 + quad * 8];
#pragma unroll
      for (int k = 0; k < 8; k++) ap[k] = (short)f2b(sp[k]);
#pragma unroll
      for (int jd = 0; jd < 4; jd++) {
        bf16x8 vf = *(const bf16x8*)&Vt[(jd * 16 + l15) * 64 + (((c * 4 + quad) ^ lh) * 8)];
        oacc[jd] = __builtin_amdgcn_mfma_f32_16x16x32_bf16(ap, vf, oacc[jd], 0, 0, 0);
      }
    }
    __syncthreads();
  }

  // ---- epilogue: ctx store (already normalized) ----
  unsigned short* Cb = Ctx + (size_t)(b * SEQ + q0 + w * 16) * HID + h * HD;
#pragma unroll
  for (int jd = 0; jd < 4; jd++)
#pragma unroll
    for (int r = 0; r < 4; r++)
      Cb[(size_t)(quad * 4 + r) * HID + jd * 16 + l15] = f2b(oacc[jd][r]);
}

// ======================= host launch =======================
extern "C" void kernel_launch(void* const* d_in, const int* in_sizes, int n_in,
                              void* d_out, int out_size, void* d_ws, size_t ws_size,
                              hipStream_t stream)
{
  const float* tgt  = (const float*)d_in[0];
  const float* enc  = (const float*)d_in[1];
  const int* tmask  = (const int*)d_in[2];
  const int* smask  = (const int*)d_in[3];
  const float* sa_wq = (const float*)d_in[4],  *sa_bq = (const float*)d_in[5];
  const float* sa_wk = (const float*)d_in[6],  *sa_bk = (const float*)d_in[7];
  const float* sa_wv = (const float*)d_in[8],  *sa_bv = (const float*)d_in[9];
  const float* sa_wo = (const float*)d_in[10], *sa_bo = (const float*)d_in[11];
  const float* ea_wq = (const float*)d_in[12], *ea_bq = (const float*)d_in[13];
  const float* ea_wk = (const float*)d_in[14], *ea_bk = (const float*)d_in[15];
  const float* ea_wv = (const float*)d_in[16], *ea_bv = (const float*)d_in[17];
  const float* ea_wo = (const float*)d_in[18], *ea_bo = (const float*)d_in[19];
  const float* ffn_w1 = (const float*)d_in[20], *ffn_b1 = (const float*)d_in[21];
  const float* ffn_w2 = (const float*)d_in[22], *ffn_b2 = (const float*)d_in[23];
  const float* ln1_g = (const float*)d_in[24], *ln1_b = (const float*)d_in[25];
  const float* ln2_g = (const float*)d_in[26], *ln2_b = (const float*)d_in[27];
  const float* ln3_g = (const float*)d_in[28], *ln3_b = (const float*)d_in[29];

  const size_t NBUF = (size_t)NB * SEQ * HID;  // 4 Mi elements
  float* out_tgt  = (float*)d_out;
  float* out_attn = (float*)d_out + NBUF;

  char* ws = (char*)d_ws;
  // R0: 0..48MB — QKVb(self, bf16 24MB) -> KVb(16MB)+Qcb(8MB) -> Hb(ffn hidden 32MB) / x2b
  unsigned short* QKVb = (unsigned short*)(ws);         // [4096,3072] bf16, 24MB
  unsigned short* KVb  = (unsigned short*)(ws);         // [4096,2048] bf16, 16MB
  unsigned short* Qcb  = (unsigned short*)(ws + 24*MB); // [4096,1024] bf16, 8MB
  unsigned short* Hb   = (unsigned short*)(ws);         // [4096,4096] bf16, 32MB
  unsigned short* x2b  = (unsigned short*)(ws + 32*MB); // 8MB
  float*          T    = (float*)(ws + 48*MB);          // 16MB
  float*          x1   = (float*)(ws + 64*MB);          // 16MB
  float*          x2   = (float*)(ws + 80*MB);          // 16MB (overlays tgtb/encb)
  unsigned short* tgtb = (unsigned short*)(ws + 80*MB); // 8MB
  unsigned short* encb = (unsigned short*)(ws + 88*MB); // 8MB
  unsigned short* ctxb = (unsigned short*)(ws + 96*MB); // 8MB (also x1b)
  unsigned short* x1b  = ctxb;
  unsigned short* qkv_t  = (unsigned short*)(ws + 104*MB); // [3072,1024] 6MB
  unsigned short* sawo_t = (unsigned short*)(ws + 110*MB); // 2MB
  unsigned short* eaq_t  = (unsigned short*)(ws + 112*MB); // 2MB
  unsigned short* eakv_t = (unsigned short*)(ws + 114*MB); // [2048,1024] 4MB
  unsigned short* eawo_t = (unsigned short*)(ws + 118*MB); // 2MB
  unsigned short* w1t    = (unsigned short*)(ws + 120*MB); // [4096,1024] 8MB
  unsigned short* w2t    = (unsigned short*)(ws + 128*MB); // [1024,4096] 8MB
  float*          b_qkv  = (float*)(ws + 136*MB);          // 3072
  float*          b_kv   = (float*)(ws + 136*MB + 16384);  // 2048

  const int M = NB * SEQ;  // 4096
  dim3 blk(256);
  dim3 g32(32, 32);

  // ---- prep: weight transpose-convert + bias pack + activation convert ----
  wconv_kernel<<<g32, blk, 0, stream>>>(sa_wq, qkv_t,                 HID, HID, HID);
  wconv_kernel<<<g32, blk, 0, stream>>>(sa_wk, qkv_t + 1024*1024,     HID, HID, HID);
  wconv_kernel<<<g32, blk, 0, stream>>>(sa_wv, qkv_t + 2048*1024,     HID, HID, HID);
  wconv_kernel<<<g32, blk, 0, stream>>>(sa_wo, sawo_t,                HID, HID, HID);
  wconv_kernel<<<g32, blk, 0, stream>>>(ea_wq, eaq_t,                 HID, HID, HID);
  wconv_kernel<<<g32, blk, 0, stream>>>(ea_wk, eakv_t,                HID, HID, HID);
  wconv_kernel<<<g32, blk, 0, stream>>>(ea_wv, eakv_t + 1024*1024,    HID, HID, HID);
  wconv_kernel<<<g32, blk, 0, stream>>>(ea_wo, eawo_t,                HID, HID, HID);
  wconv_kernel<<<dim3(128, 32), blk, 0, stream>>>(ffn_w1, w1t, HID, PF, HID);
  wconv_kernel<<<dim3(32, 128), blk, 0, stream>>>(ffn_w2, w2t, PF, HID, PF);
  copyf_kernel<<<4, blk, 0, stream>>>(sa_bq, b_qkv, 1024);
  copyf_kernel<<<4, blk, 0, stream>>>(sa_bk, b_qkv + 1024, 1024);
  copyf_kernel<<<4, blk, 0, stream>>>(sa_bv, b_qkv + 2048, 1024);
  copyf_kernel<<<4, blk, 0, stream>>>(ea_bk, b_kv, 1024);
  copyf_kernel<<<4, blk, 0, stream>>>(ea_bv, b_kv + 1024, 1024);
  f2b_kernel<<<4096, blk, 0, stream>>>(tgt, tgtb, 1024*1024);
  f2b_kernel<<<4096, blk, 0, stream>>>(enc, encb, 1024*1024);

  // ---- self-attention (bf16 QKV + MFMA flash) ----
  gemm_bf16<<<dim3(3072/128, M/128), blk, 0, stream>>>(tgtb, qkv_t, b_qkv, nullptr, QKVb, M, 3072, HID, 0);
  flash_attn_mfma<<<dim3(1024), blk, 0, stream>>>(QKVb, tmask, ctxb);
  gemm_bf16<<<dim3(HID/128, M/128), blk, 0, stream>>>(ctxb, sawo_t, sa_bo, T, nullptr, M, HID, HID, 0);
  add_ln_kernel<<<M, blk, 0, stream>>>(tgt, T, ln1_g, ln1_b, x1, x1b);

  // ---- cross-attention (fused: scores+softmax+P-write+PV) ----
  gemm_bf16<<<dim3(2048/128, M/128), blk, 0, stream>>>(encb, eakv_t, b_kv, nullptr, KVb, M, 2048, HID, 0);
  gemm_bf16<<<dim3(HID/128, M/128), blk, 0, stream>>>(x1b, eaq_t, ea_bq, nullptr, Qcb, M, HID, HID, 0);
  cross_attn_fused<<<dim3(1024), blk, 0, stream>>>(Qcb, KVb, smask, out_attn, ctxb);
  gemm_bf16<<<dim3(HID/128, M/128), blk, 0, stream>>>(ctxb, eawo_t, ea_bo, T, nullptr, M, HID, HID, 0);
  add_ln_kernel<<<M, blk, 0, stream>>>(x1, T, ln2_g, ln2_b, x2, x2b);

  // ---- FFN ----
  gemm_bf16<<<dim3(PF/128, M/128), blk, 0, stream>>>(x2b, w1t, ffn_b1, nullptr, Hb, M, PF, HID, 1);
  gemm_bf16<<<dim3(HID/128, M/128), blk, 0, stream>>>(Hb, w2t, ffn_b2, T, nullptr, M, HID, PF, 0);
  add_ln_kernel<<<M, blk, 0, stream>>>(x2, T, ln3_g, ln3_b, out_tgt, nullptr);
}